// Round 1
// baseline (2154.313 us; speedup 1.0000x reference)
//
#include <hip/hip_runtime.h>
#include <hip/hip_bf16.h>
#include <math.h>

// GraphEncoder: 3x GCNConv (relu) -> global_mean_pool -> two linear heads.
// N=100000 nodes, E=1600000 edges, G=2048 graphs, feats 10->128->256->256->64(x2)
//
// Strategy:
//  - deg = 1 + indeg via int atomics; dis = rsqrt(deg)
//  - build incoming-edge CSR on device (histogram + single-block scan + fill)
//  - transform kernels scale each output row by dis[row]  (T' = (h@W) * dis)
//    => agg[i] = relu( (sum_{j in N(i)} T'[j] + T'[i]) * dis[i] + b )
//  - aggregation gathers full rows (coalesced 512B/1KB reads, L3-resident)
//  - batch is sorted: graph ranges via histogram+scan, direct mean pool
//  - heads: per-graph 256->64 x2 in one small kernel

#define THREADS 256

// ---------------- init ----------------
__global__ void init_kernel(int* deg, int* gcnt, int n, int g) {
    int i = blockIdx.x * blockDim.x + threadIdx.x;
    if (i < n) deg[i] = 1;          // self-loop
    if (i < g) gcnt[i] = 0;
}

__global__ void count_deg_kernel(const int* dst, int* deg, int e) {
    int i = blockIdx.x * blockDim.x + threadIdx.x;
    if (i < e) atomicAdd(&deg[dst[i]], 1);
}

__global__ void dis_kernel(const int* deg, float* dis, int n) {
    int i = blockIdx.x * blockDim.x + threadIdx.x;
    if (i < n) dis[i] = rsqrtf((float)deg[i]);
}

// single-block exclusive scan; out has n+1 entries (out[n] = total)
__global__ void exscan_kernel(const int* in, int* out, int n, int sub) {
    __shared__ int buf[1024];
    int carry = 0;
    for (int base = 0; base < n; base += 1024) {
        __syncthreads();
        int i = base + threadIdx.x;
        int v = (i < n) ? (in[i] - sub) : 0;
        buf[threadIdx.x] = v;
        __syncthreads();
        for (int off = 1; off < 1024; off <<= 1) {
            int t = (threadIdx.x >= off) ? buf[threadIdx.x - off] : 0;
            __syncthreads();
            buf[threadIdx.x] += t;
            __syncthreads();
        }
        if (i < n) out[i] = carry + buf[threadIdx.x] - v;
        carry += buf[1023];
    }
    if (threadIdx.x == 0) out[n] = carry;
}

__global__ void copy_int_kernel(const int* src, int* dst, int n) {
    int i = blockIdx.x * blockDim.x + threadIdx.x;
    if (i < n) dst[i] = src[i];
}

__global__ void fill_csr_kernel(const int* src, const int* dst, int* cursor,
                                int* col, int e) {
    int i = blockIdx.x * blockDim.x + threadIdx.x;
    if (i < e) {
        int d = dst[i];
        int pos = atomicAdd(&cursor[d], 1);
        col[pos] = src[i];
    }
}

__global__ void batch_hist_kernel(const int* batch, int* gcnt, int n) {
    int i = blockIdx.x * blockDim.x + threadIdx.x;
    if (i < n) atomicAdd(&gcnt[batch[i]], 1);
}

// ---------------- layer 1 transform: [N,10] @ [10,128], row-scaled ----------------
__global__ __launch_bounds__(THREADS) void transform1_kernel(
        const float* __restrict__ x, const float* __restrict__ W,
        const float* __restrict__ dis, float* __restrict__ out, int n) {
    int t = blockIdx.x * blockDim.x + threadIdx.x;
    if (t >= n * 128) return;
    int r = t >> 7;
    int c = t & 127;
    float acc = 0.f;
#pragma unroll
    for (int k = 0; k < 10; ++k)
        acc = fmaf(x[r * 10 + k], W[k * 128 + c], acc);
    out[(size_t)r * 128 + c] = acc * dis[r];
}

// ---------------- tiled transform: [N,K] @ [K,256], row-scaled ----------------
template <int K>
__global__ __launch_bounds__(THREADS) void transform_kernel(
        const float* __restrict__ H, const float* __restrict__ W,
        const float* __restrict__ dis, float* __restrict__ out, int n) {
    __shared__ __align__(16) float hs[16 * K];
    const int r0 = blockIdx.x * 16;
    const int c  = threadIdx.x;          // 256 cols

    // stage 16 rows of H into LDS (float4, coalesced)
    const int vecs = 16 * K / 4;
    const float4* src4 = reinterpret_cast<const float4*>(H + (size_t)r0 * K);
    float4* dst4 = reinterpret_cast<float4*>(hs);
    for (int idx = threadIdx.x; idx < vecs; idx += THREADS) {
        int row = r0 + idx / (K / 4);
        dst4[idx] = (row < n) ? src4[idx] : make_float4(0.f, 0.f, 0.f, 0.f);
    }
    __syncthreads();

    float acc[16];
#pragma unroll
    for (int r = 0; r < 16; ++r) acc[r] = 0.f;

    for (int kk = 0; kk < K; kk += 4) {
        float w0 = W[(kk + 0) * 256 + c];
        float w1 = W[(kk + 1) * 256 + c];
        float w2 = W[(kk + 2) * 256 + c];
        float w3 = W[(kk + 3) * 256 + c];
#pragma unroll
        for (int r = 0; r < 16; ++r) {
            float4 h4 = *reinterpret_cast<const float4*>(&hs[r * K + kk]);
            acc[r] = fmaf(h4.x, w0, acc[r]);
            acc[r] = fmaf(h4.y, w1, acc[r]);
            acc[r] = fmaf(h4.z, w2, acc[r]);
            acc[r] = fmaf(h4.w, w3, acc[r]);
        }
    }

#pragma unroll
    for (int r = 0; r < 16; ++r) {
        int row = r0 + r;
        if (row < n) out[(size_t)row * 256 + c] = acc[r] * dis[row];
    }
}

// ---------------- aggregation: out[i] = relu((sum T'[nbr] + T'[i]) * dis[i] + b) ----------------
template <int F>
__global__ __launch_bounds__(THREADS) void agg_kernel(
        const float* __restrict__ T, const int* __restrict__ row_ptr,
        const int* __restrict__ col, const float* __restrict__ dis,
        const float* __restrict__ b, float* __restrict__ out, int n) {
    const int NPB = THREADS / F;
    int node = blockIdx.x * NPB + threadIdx.x / F;
    int c = threadIdx.x % F;
    if (node >= n) return;

    float acc = T[(size_t)node * F + c];   // self-loop term (already *dis[node])
    int s = row_ptr[node], e = row_ptr[node + 1];
    for (int p = s; p < e; ++p) {
        int j = col[p];
        acc += T[(size_t)j * F + c];
    }
    float o = acc * dis[node] + b[c];
    out[(size_t)node * F + c] = fmaxf(o, 0.f);
}

// ---------------- mean pool over sorted batch ranges ----------------
__global__ __launch_bounds__(THREADS) void pool_kernel(
        const float* __restrict__ H, const int* __restrict__ goff,
        float* __restrict__ pooled) {
    int g = blockIdx.x;
    int c = threadIdx.x;
    int s = goff[g], e = goff[g + 1];
    float acc = 0.f;
    for (int r = s; r < e; ++r) acc += H[(size_t)r * 256 + c];
    float cnt = (float)(e - s);
    pooled[(size_t)g * 256 + c] = acc / fmaxf(cnt, 1.0f);
}

// ---------------- heads: pooled @ Wmu + bmu, pooled @ Wlv + blv ----------------
__global__ __launch_bounds__(128) void heads_kernel(
        const float* __restrict__ pooled,
        const float* __restrict__ Wmu, const float* __restrict__ bmu,
        const float* __restrict__ Wlv, const float* __restrict__ blv,
        float* __restrict__ out, int g_total) {
    __shared__ float p[256];
    int g = blockIdx.x;
    for (int k = threadIdx.x; k < 256; k += 128) p[k] = pooled[(size_t)g * 256 + k];
    __syncthreads();
    int c = threadIdx.x & 63;
    bool is_mu = threadIdx.x < 64;
    const float* W = is_mu ? Wmu : Wlv;
    const float* bb = is_mu ? bmu : blv;
    float acc = 0.f;
    for (int k = 0; k < 256; ++k) acc = fmaf(p[k], W[k * 64 + c], acc);
    float* o = is_mu ? (out + (size_t)g * 64) : (out + (size_t)g_total * 64 + (size_t)g * 64);
    o[c] = acc + bb[c];
}

extern "C" void kernel_launch(void* const* d_in, const int* in_sizes, int n_in,
                              void* d_out, int out_size, void* d_ws, size_t ws_size,
                              hipStream_t stream) {
    const float* x      = (const float*)d_in[0];
    const int*   eidx   = (const int*)d_in[1];
    const int*   batch  = (const int*)d_in[2];
    const float* W1  = (const float*)d_in[3];
    const float* b1  = (const float*)d_in[4];
    const float* W2  = (const float*)d_in[5];
    const float* b2  = (const float*)d_in[6];
    const float* W3  = (const float*)d_in[7];
    const float* b3  = (const float*)d_in[8];
    const float* Wmu = (const float*)d_in[9];
    const float* bmu = (const float*)d_in[10];
    const float* Wlv = (const float*)d_in[11];
    const float* blv = (const float*)d_in[12];
    float* out = (float*)d_out;

    const int N = in_sizes[0] / 10;
    const int E = in_sizes[1] / 2;
    const int G = out_size / 128;

    const int* src = eidx;       // edge_index[0]
    const int* dst = eidx + E;   // edge_index[1]

    // workspace carve-up
    float* A      = (float*)d_ws;            // [N,256] transformed (row-scaled)
    float* B      = A + (size_t)N * 256;     // [N,256] layer output
    float* dis    = B + (size_t)N * 256;     // [N]
    float* pooled = dis + N;                 // [G,256]
    int* deg     = (int*)(pooled + (size_t)G * 256); // [N]
    int* row_ptr = deg + N;                  // [N+1]
    int* cursor  = row_ptr + N + 1;          // [N]
    int* col     = cursor + N;               // [E]
    int* gcnt    = col + E;                  // [G]
    int* goff    = gcnt + G;                 // [G+1]

    const int nb_n  = (N + THREADS - 1) / THREADS;
    const int nb_e  = (E + THREADS - 1) / THREADS;

    // degree + norms + CSR + graph ranges
    init_kernel<<<nb_n, THREADS, 0, stream>>>(deg, gcnt, N, G);
    count_deg_kernel<<<nb_e, THREADS, 0, stream>>>(dst, deg, E);
    dis_kernel<<<nb_n, THREADS, 0, stream>>>(deg, dis, N);
    exscan_kernel<<<1, 1024, 0, stream>>>(deg, row_ptr, N, 1);   // indeg = deg-1
    copy_int_kernel<<<nb_n, THREADS, 0, stream>>>(row_ptr, cursor, N);
    fill_csr_kernel<<<nb_e, THREADS, 0, stream>>>(src, dst, cursor, col, E);
    batch_hist_kernel<<<nb_n, THREADS, 0, stream>>>(batch, gcnt, N);
    exscan_kernel<<<1, 1024, 0, stream>>>(gcnt, goff, G, 0);

    // layer 1: 10 -> 128
    transform1_kernel<<<(N * 128 + THREADS - 1) / THREADS, THREADS, 0, stream>>>(x, W1, dis, A, N);
    agg_kernel<128><<<(N + 1) / 2, THREADS, 0, stream>>>(A, row_ptr, col, dis, b1, B, N);

    // layer 2: 128 -> 256
    transform_kernel<128><<<(N + 15) / 16, THREADS, 0, stream>>>(B, W2, dis, A, N);
    agg_kernel<256><<<N, THREADS, 0, stream>>>(A, row_ptr, col, dis, b2, B, N);

    // layer 3: 256 -> 256
    transform_kernel<256><<<(N + 15) / 16, THREADS, 0, stream>>>(B, W3, dis, A, N);
    agg_kernel<256><<<N, THREADS, 0, stream>>>(A, row_ptr, col, dis, b3, B, N);

    // mean pool + heads
    pool_kernel<<<G, THREADS, 0, stream>>>(B, goff, pooled);
    heads_kernel<<<G, 128, 0, stream>>>(pooled, Wmu, bmu, Wlv, blv, out, G);
}

// Round 2
// 1119.885 us; speedup vs baseline: 1.9237x; 1.9237x over previous
//
#include <hip/hip_runtime.h>
#include <hip/hip_bf16.h>
#include <math.h>

// GraphEncoder: 3x GCNConv (relu) -> global_mean_pool -> two linear heads.
// N=100000, E=1600000, G=2048, feats 10->128->256->256->64(x2)
//
// Round-2 strategy:
//  - aggregate-then-transform: A(HW) == (AH)W, so gather the narrow input
//    (10 / 128 / 256 cols) instead of the wide output. Gather volume 4.3GB->2.7GB.
//  - agg kernels: float4 lanes, neighbor loop unrolled x8 for memory-level
//    parallelism (round-1 agg had VGPR=8, ~1 gather in flight -> latency-bound).
//  - transform epilogue fuses bias + relu + dis row-scale for the next gather.
//  - shfl-based exclusive scan (2 barriers per 4096-chunk vs 20 per 1024).

#define THREADS 256

// ---------------- init ----------------
__global__ void init_kernel(int* deg, int* gcnt, int n, int g) {
    int i = blockIdx.x * blockDim.x + threadIdx.x;
    if (i < n) deg[i] = 1;          // self-loop
    if (i < g) gcnt[i] = 0;
}

__global__ void count_deg_kernel(const int* dst, int* deg, int e) {
    int i = blockIdx.x * blockDim.x + threadIdx.x;
    if (i < e) atomicAdd(&deg[dst[i]], 1);
}

__global__ void dis_kernel(const int* deg, float* dis, int n) {
    int i = blockIdx.x * blockDim.x + threadIdx.x;
    if (i < n) dis[i] = rsqrtf((float)deg[i]);
}

// single-block exclusive scan, 1024 thr x 4 elems/chunk, wave-shfl based.
// out has n+1 entries (out[n] = total).
__global__ __launch_bounds__(1024) void exscan_kernel(const int* in, int* out, int n, int sub) {
    __shared__ int wsum[16];
    int carry = 0;
    const int lane = threadIdx.x & 63;
    const int wid = threadIdx.x >> 6;
    for (int base = 0; base < n; base += 4096) {
        int i0 = base + threadIdx.x * 4;
        int v[4];
#pragma unroll
        for (int q = 0; q < 4; ++q) {
            int i = i0 + q;
            v[q] = (i < n) ? (in[i] - sub) : 0;
        }
        int tsum = v[0] + v[1] + v[2] + v[3];
        int incl = tsum;
#pragma unroll
        for (int off = 1; off < 64; off <<= 1) {
            int t = __shfl_up(incl, off, 64);
            if (lane >= off) incl += t;
        }
        if (lane == 63) wsum[wid] = incl;
        __syncthreads();
        int wbase = 0;
        for (int w = 0; w < wid; ++w) wbase += wsum[w];
        int pos = incl - tsum + wbase + carry;
#pragma unroll
        for (int q = 0; q < 4; ++q) {
            int i = i0 + q;
            if (i < n) out[i] = pos;
            pos += v[q];
        }
        int tot = 0;
        for (int w = 0; w < 16; ++w) tot += wsum[w];
        carry += tot;
        __syncthreads();
    }
    if (threadIdx.x == 0) out[n] = carry;
}

__global__ void copy_int_kernel(const int* src, int* dst, int n) {
    int i = blockIdx.x * blockDim.x + threadIdx.x;
    if (i < n) dst[i] = src[i];
}

__global__ void fill_csr_kernel(const int* src, const int* dst, int* cursor,
                                int* col, int e) {
    int i = blockIdx.x * blockDim.x + threadIdx.x;
    if (i < e) {
        int d = dst[i];
        int pos = atomicAdd(&cursor[d], 1);
        col[pos] = src[i];
    }
}

__global__ void batch_hist_kernel(const int* batch, int* gcnt, int n) {
    int i = blockIdx.x * blockDim.x + threadIdx.x;
    if (i < n) atomicAdd(&gcnt[batch[i]], 1);
}

// ---------------- S0 = x * dis[row]  ([N,10]) ----------------
__global__ void scale0_kernel(const float* __restrict__ x, const float* __restrict__ dis,
                              float* __restrict__ out, int total) {
    int i = blockIdx.x * blockDim.x + threadIdx.x;
    if (i < total) out[i] = x[i] * dis[i / 10];
}

// ---------------- agg over 10-col rows (16 lanes/node) ----------------
__global__ __launch_bounds__(THREADS) void agg10_kernel(
        const float* __restrict__ S, const int* __restrict__ row_ptr,
        const int* __restrict__ col, const float* __restrict__ dis,
        float* __restrict__ out, int n) {
    int node = blockIdx.x * 16 + threadIdx.x / 16;
    if (node >= n) return;
    int lane = threadIdx.x % 16;
    bool act = lane < 10;
    float acc = act ? S[(size_t)node * 10 + lane] : 0.f;
    int s = row_ptr[node], e = row_ptr[node + 1];
    int p = s;
    for (; p + 4 <= e; p += 4) {
        int j[4];
#pragma unroll
        for (int q = 0; q < 4; ++q) j[q] = col[p + q];
        float v[4];
#pragma unroll
        for (int q = 0; q < 4; ++q) v[q] = act ? S[(size_t)j[q] * 10 + lane] : 0.f;
        acc += v[0] + v[1] + v[2] + v[3];
    }
    for (; p < e; ++p) {
        int j = col[p];
        if (act) acc += S[(size_t)j * 10 + lane];
    }
    if (act) out[(size_t)node * 10 + lane] = acc * dis[node];
}

// ---------------- agg over K-col rows, float4 lanes, unroll 8 ----------------
template <int K, int L>   // L lanes per node, L*4 == K
__global__ __launch_bounds__(THREADS) void agg_vec_kernel(
        const float* __restrict__ S, const int* __restrict__ row_ptr,
        const int* __restrict__ col, const float* __restrict__ dis,
        float* __restrict__ out, int n) {
    static_assert(L * 4 == K, "");
    constexpr int stride = K / 4;
    int node = blockIdx.x * (THREADS / L) + threadIdx.x / L;
    if (node >= n) return;
    int lane = threadIdx.x % L;
    const float4* S4 = reinterpret_cast<const float4*>(S);

    float4 a = S4[(size_t)node * stride + lane];
    float acc0 = a.x, acc1 = a.y, acc2 = a.z, acc3 = a.w;

    int s = row_ptr[node], e = row_ptr[node + 1];
    int p = s;
    for (; p + 8 <= e; p += 8) {
        int j[8];
#pragma unroll
        for (int q = 0; q < 8; ++q) j[q] = col[p + q];
        float4 v[8];
#pragma unroll
        for (int q = 0; q < 8; ++q) v[q] = S4[(size_t)j[q] * stride + lane];
#pragma unroll
        for (int q = 0; q < 8; ++q) {
            acc0 += v[q].x; acc1 += v[q].y; acc2 += v[q].z; acc3 += v[q].w;
        }
    }
    for (; p + 2 <= e; p += 2) {
        int j0 = col[p], j1 = col[p + 1];
        float4 v0 = S4[(size_t)j0 * stride + lane];
        float4 v1 = S4[(size_t)j1 * stride + lane];
        acc0 += v0.x + v1.x; acc1 += v0.y + v1.y;
        acc2 += v0.z + v1.z; acc3 += v0.w + v1.w;
    }
    for (; p < e; ++p) {
        float4 v = S4[(size_t)col[p] * stride + lane];
        acc0 += v.x; acc1 += v.y; acc2 += v.z; acc3 += v.w;
    }
    float d = dis[node];
    float4 o = make_float4(acc0 * d, acc1 * d, acc2 * d, acc3 * d);
    reinterpret_cast<float4*>(out)[(size_t)node * stride + lane] = o;
}

// ---------------- layer-1 transform: [N,10] @ [10,128] + b, relu, *dis ----------------
__global__ __launch_bounds__(THREADS) void transform1_kernel(
        const float* __restrict__ A0, const float* __restrict__ W,
        const float* __restrict__ b, const float* __restrict__ dis,
        float* __restrict__ out, int n) {
    int t = blockIdx.x * blockDim.x + threadIdx.x;
    if (t >= n * 128) return;
    int r = t >> 7;
    int c = t & 127;
    float acc = b[c];
#pragma unroll
    for (int k = 0; k < 10; ++k)
        acc = fmaf(A0[(size_t)r * 10 + k], W[k * 128 + c], acc);
    out[(size_t)r * 128 + c] = fmaxf(acc, 0.f) * dis[r];
}

// ---------------- tiled transform: [N,K] @ [K,256] + b, relu, optional *dis ----------------
template <int K, bool SCALE>
__global__ __launch_bounds__(THREADS) void transform_kernel(
        const float* __restrict__ H, const float* __restrict__ W,
        const float* __restrict__ b, const float* __restrict__ dis,
        float* __restrict__ out, int n) {
    __shared__ __align__(16) float hs[16 * K];
    const int r0 = blockIdx.x * 16;
    const int c  = threadIdx.x;          // 256 cols

    const int vecs = 16 * K / 4;
    const float4* src4 = reinterpret_cast<const float4*>(H + (size_t)r0 * K);
    float4* dst4 = reinterpret_cast<float4*>(hs);
    for (int idx = threadIdx.x; idx < vecs; idx += THREADS) {
        int row = r0 + idx / (K / 4);
        dst4[idx] = (row < n) ? src4[idx] : make_float4(0.f, 0.f, 0.f, 0.f);
    }
    __syncthreads();

    float acc[16];
#pragma unroll
    for (int r = 0; r < 16; ++r) acc[r] = 0.f;

    for (int kk = 0; kk < K; kk += 4) {
        float w0 = W[(kk + 0) * 256 + c];
        float w1 = W[(kk + 1) * 256 + c];
        float w2 = W[(kk + 2) * 256 + c];
        float w3 = W[(kk + 3) * 256 + c];
#pragma unroll
        for (int r = 0; r < 16; ++r) {
            float4 h4 = *reinterpret_cast<const float4*>(&hs[r * K + kk]);
            acc[r] = fmaf(h4.x, w0, acc[r]);
            acc[r] = fmaf(h4.y, w1, acc[r]);
            acc[r] = fmaf(h4.z, w2, acc[r]);
            acc[r] = fmaf(h4.w, w3, acc[r]);
        }
    }

    float bias = b[c];
#pragma unroll
    for (int r = 0; r < 16; ++r) {
        int row = r0 + r;
        if (row < n) {
            float o = fmaxf(acc[r] + bias, 0.f);
            if (SCALE) o *= dis[row];
            out[(size_t)row * 256 + c] = o;
        }
    }
}

// ---------------- mean pool over sorted batch ranges ----------------
__global__ __launch_bounds__(THREADS) void pool_kernel(
        const float* __restrict__ H, const int* __restrict__ goff,
        float* __restrict__ pooled) {
    int g = blockIdx.x;
    int c = threadIdx.x;
    int s = goff[g], e = goff[g + 1];
    float acc = 0.f;
    for (int r = s; r < e; ++r) acc += H[(size_t)r * 256 + c];
    float cnt = (float)(e - s);
    pooled[(size_t)g * 256 + c] = acc / fmaxf(cnt, 1.0f);
}

// ---------------- heads ----------------
__global__ __launch_bounds__(128) void heads_kernel(
        const float* __restrict__ pooled,
        const float* __restrict__ Wmu, const float* __restrict__ bmu,
        const float* __restrict__ Wlv, const float* __restrict__ blv,
        float* __restrict__ out, int g_total) {
    __shared__ float p[256];
    int g = blockIdx.x;
    for (int k = threadIdx.x; k < 256; k += 128) p[k] = pooled[(size_t)g * 256 + k];
    __syncthreads();
    int c = threadIdx.x & 63;
    bool is_mu = threadIdx.x < 64;
    const float* W = is_mu ? Wmu : Wlv;
    const float* bb = is_mu ? bmu : blv;
    float acc = 0.f;
    for (int k = 0; k < 256; ++k) acc = fmaf(p[k], W[k * 64 + c], acc);
    float* o = is_mu ? (out + (size_t)g * 64) : (out + (size_t)g_total * 64 + (size_t)g * 64);
    o[c] = acc + bb[c];
}

extern "C" void kernel_launch(void* const* d_in, const int* in_sizes, int n_in,
                              void* d_out, int out_size, void* d_ws, size_t ws_size,
                              hipStream_t stream) {
    const float* x      = (const float*)d_in[0];
    const int*   eidx   = (const int*)d_in[1];
    const int*   batch  = (const int*)d_in[2];
    const float* W1  = (const float*)d_in[3];
    const float* b1  = (const float*)d_in[4];
    const float* W2  = (const float*)d_in[5];
    const float* b2  = (const float*)d_in[6];
    const float* W3  = (const float*)d_in[7];
    const float* b3  = (const float*)d_in[8];
    const float* Wmu = (const float*)d_in[9];
    const float* bmu = (const float*)d_in[10];
    const float* Wlv = (const float*)d_in[11];
    const float* blv = (const float*)d_in[12];
    float* out = (float*)d_out;

    const int N = in_sizes[0] / 10;
    const int E = in_sizes[1] / 2;
    const int G = out_size / 128;

    const int* src = eidx;       // edge_index[0]
    const int* dst = eidx + E;   // edge_index[1]

    // workspace carve-up
    float* A      = (float*)d_ws;            // [N,256] ping
    float* B      = A + (size_t)N * 256;     // [N,256] pong
    float* dis    = B + (size_t)N * 256;     // [N]
    float* pooled = dis + N;                 // [G,256]
    int* deg     = (int*)(pooled + (size_t)G * 256); // [N]
    int* row_ptr = deg + N;                  // [N+1]
    int* cursor  = row_ptr + N + 1;          // [N]
    int* col     = cursor + N;               // [E]
    int* gcnt    = col + E;                  // [G]
    int* goff    = gcnt + G;                 // [G+1]

    const int nb_n = (N + THREADS - 1) / THREADS;
    const int nb_e = (E + THREADS - 1) / THREADS;

    // degree + norms + CSR + graph ranges
    init_kernel<<<nb_n, THREADS, 0, stream>>>(deg, gcnt, N, G);
    count_deg_kernel<<<nb_e, THREADS, 0, stream>>>(dst, deg, E);
    dis_kernel<<<nb_n, THREADS, 0, stream>>>(deg, dis, N);
    exscan_kernel<<<1, 1024, 0, stream>>>(deg, row_ptr, N, 1);   // indeg = deg-1
    copy_int_kernel<<<nb_n, THREADS, 0, stream>>>(row_ptr, cursor, N);
    fill_csr_kernel<<<nb_e, THREADS, 0, stream>>>(src, dst, cursor, col, E);
    batch_hist_kernel<<<nb_n, THREADS, 0, stream>>>(batch, gcnt, N);
    exscan_kernel<<<1, 1024, 0, stream>>>(gcnt, goff, G, 0);

    // layer 1: aggregate x*dis (10 cols) then transform 10->128
    scale0_kernel<<<(N * 10 + THREADS - 1) / THREADS, THREADS, 0, stream>>>(x, dis, A, N * 10);
    agg10_kernel<<<(N + 15) / 16, THREADS, 0, stream>>>(A, row_ptr, col, dis, B, N);
    transform1_kernel<<<((size_t)N * 128 + THREADS - 1) / THREADS, THREADS, 0, stream>>>(B, W1, b1, dis, A, N);

    // layer 2: aggregate S1 (128 cols) then transform 128->256
    agg_vec_kernel<128, 32><<<(N + 7) / 8, THREADS, 0, stream>>>(A, row_ptr, col, dis, B, N);
    transform_kernel<128, true><<<(N + 15) / 16, THREADS, 0, stream>>>(B, W2, b2, dis, A, N);

    // layer 3: aggregate S2 (256 cols) then transform 256->256
    agg_vec_kernel<256, 64><<<(N + 3) / 4, THREADS, 0, stream>>>(A, row_ptr, col, dis, B, N);
    transform_kernel<256, false><<<(N + 15) / 16, THREADS, 0, stream>>>(B, W3, b3, dis, A, N);

    // mean pool + heads
    pool_kernel<<<G, THREADS, 0, stream>>>(A, goff, pooled);
    heads_kernel<<<G, 128, 0, stream>>>(pooled, Wmu, bmu, Wlv, blv, out, G);
}

// Round 3
// 804.752 us; speedup vs baseline: 2.6770x; 1.3916x over previous
//
#include <hip/hip_runtime.h>
#include <hip/hip_bf16.h>
#include <math.h>

// GraphEncoder: 3x GCNConv (relu) -> global_mean_pool -> two linear heads.
// N=100000, E=1600000, G=2048, feats 10->128->256->256->64(x2)
//
// Round-3 strategy:
//  - inter-layer activations stored bf16 (RNE) -> agg gather bytes halve again
//  - transforms for 128->256 / 256->256 use mfma_f32_16x16x32_bf16, fp32 accum:
//    per-wave 16 rows x 256 cols, A-frags from global (L3-resident),
//    B-frags from pre-transposed bf16 W^T[256][K] (L2-hot)
//  - layer-1 (K=10) path, pool, heads remain fp32

#define THREADS 256

typedef __attribute__((ext_vector_type(8))) short bf16x8;
typedef __attribute__((ext_vector_type(4))) float f32x4;

// ---------------- init ----------------
__global__ void init_kernel(int* deg, int* gcnt, int n, int g) {
    int i = blockIdx.x * blockDim.x + threadIdx.x;
    if (i < n) deg[i] = 1;          // self-loop
    if (i < g) gcnt[i] = 0;
}

__global__ void count_deg_kernel(const int* dst, int* deg, int e) {
    int i = blockIdx.x * blockDim.x + threadIdx.x;
    if (i < e) atomicAdd(&deg[dst[i]], 1);
}

__global__ void dis_kernel(const int* deg, float* dis, int n) {
    int i = blockIdx.x * blockDim.x + threadIdx.x;
    if (i < n) dis[i] = rsqrtf((float)deg[i]);
}

// single-block exclusive scan, 1024 thr x 4 elems/chunk, wave-shfl based.
__global__ __launch_bounds__(1024) void exscan_kernel(const int* in, int* out, int n, int sub) {
    __shared__ int wsum[16];
    int carry = 0;
    const int lane = threadIdx.x & 63;
    const int wid = threadIdx.x >> 6;
    for (int base = 0; base < n; base += 4096) {
        int i0 = base + threadIdx.x * 4;
        int v[4];
#pragma unroll
        for (int q = 0; q < 4; ++q) {
            int i = i0 + q;
            v[q] = (i < n) ? (in[i] - sub) : 0;
        }
        int tsum = v[0] + v[1] + v[2] + v[3];
        int incl = tsum;
#pragma unroll
        for (int off = 1; off < 64; off <<= 1) {
            int t = __shfl_up(incl, off, 64);
            if (lane >= off) incl += t;
        }
        if (lane == 63) wsum[wid] = incl;
        __syncthreads();
        int wbase = 0;
        for (int w = 0; w < wid; ++w) wbase += wsum[w];
        int pos = incl - tsum + wbase + carry;
#pragma unroll
        for (int q = 0; q < 4; ++q) {
            int i = i0 + q;
            if (i < n) out[i] = pos;
            pos += v[q];
        }
        int tot = 0;
        for (int w = 0; w < 16; ++w) tot += wsum[w];
        carry += tot;
        __syncthreads();
    }
    if (threadIdx.x == 0) out[n] = carry;
}

__global__ void copy_int_kernel(const int* src, int* dst, int n) {
    int i = blockIdx.x * blockDim.x + threadIdx.x;
    if (i < n) dst[i] = src[i];
}

__global__ void fill_csr_kernel(const int* src, const int* dst, int* cursor,
                                int* col, int e) {
    int i = blockIdx.x * blockDim.x + threadIdx.x;
    if (i < e) {
        int d = dst[i];
        int pos = atomicAdd(&cursor[d], 1);
        col[pos] = src[i];
    }
}

__global__ void batch_hist_kernel(const int* batch, int* gcnt, int n) {
    int i = blockIdx.x * blockDim.x + threadIdx.x;
    if (i < n) atomicAdd(&gcnt[batch[i]], 1);
}

// ---------------- W [K][256] f32 -> WT [256][K] bf16 ----------------
__global__ void wt_kernel(const float* __restrict__ W, __hip_bfloat16* __restrict__ WT, int K) {
    int i = blockIdx.x * blockDim.x + threadIdx.x;
    if (i < K * 256) {
        int k = i >> 8;
        int c = i & 255;
        WT[c * K + k] = __float2bfloat16(W[i]);
    }
}

// ---------------- S0 = x * dis[row]  ([N,10] f32) ----------------
__global__ void scale0_kernel(const float* __restrict__ x, const float* __restrict__ dis,
                              float* __restrict__ out, int total) {
    int i = blockIdx.x * blockDim.x + threadIdx.x;
    if (i < total) out[i] = x[i] * dis[i / 10];
}

// ---------------- agg over 10-col f32 rows (16 lanes/node) ----------------
__global__ __launch_bounds__(THREADS) void agg10_kernel(
        const float* __restrict__ S, const int* __restrict__ row_ptr,
        const int* __restrict__ col, const float* __restrict__ dis,
        float* __restrict__ out, int n) {
    int node = blockIdx.x * 16 + threadIdx.x / 16;
    if (node >= n) return;
    int lane = threadIdx.x % 16;
    bool act = lane < 10;
    float acc = act ? S[(size_t)node * 10 + lane] : 0.f;
    int s = row_ptr[node], e = row_ptr[node + 1];
    int p = s;
    for (; p + 4 <= e; p += 4) {
        int j[4];
#pragma unroll
        for (int q = 0; q < 4; ++q) j[q] = col[p + q];
        float v[4];
#pragma unroll
        for (int q = 0; q < 4; ++q) v[q] = act ? S[(size_t)j[q] * 10 + lane] : 0.f;
        acc += v[0] + v[1] + v[2] + v[3];
    }
    for (; p < e; ++p) {
        int j = col[p];
        if (act) acc += S[(size_t)j * 10 + lane];
    }
    if (act) out[(size_t)node * 10 + lane] = acc * dis[node];
}

// ---------------- bf16 helpers ----------------
__device__ __forceinline__ void acc8(float* acc, uint4 v) {
    acc[0] += __uint_as_float(v.x << 16);
    acc[1] += __uint_as_float(v.x & 0xffff0000u);
    acc[2] += __uint_as_float(v.y << 16);
    acc[3] += __uint_as_float(v.y & 0xffff0000u);
    acc[4] += __uint_as_float(v.z << 16);
    acc[5] += __uint_as_float(v.z & 0xffff0000u);
    acc[6] += __uint_as_float(v.w << 16);
    acc[7] += __uint_as_float(v.w & 0xffff0000u);
}

__device__ __forceinline__ unsigned pack2(float a, float b) {
    unsigned short ua = __builtin_bit_cast(unsigned short, __float2bfloat16(a));
    unsigned short ub = __builtin_bit_cast(unsigned short, __float2bfloat16(b));
    return (unsigned)ua | ((unsigned)ub << 16);
}

// ---------------- agg over COLS-col bf16 rows; L = COLS/8 lanes/node ----------------
template <int COLS, int L>
__global__ __launch_bounds__(THREADS) void agg_bf16_kernel(
        const __hip_bfloat16* __restrict__ S, const int* __restrict__ row_ptr,
        const int* __restrict__ col, const float* __restrict__ dis,
        __hip_bfloat16* __restrict__ out, int n) {
    static_assert(L * 8 == COLS, "");
    constexpr int stride = COLS / 8;       // uint4 per row
    int node = blockIdx.x * (THREADS / L) + threadIdx.x / L;
    if (node >= n) return;
    int lane = threadIdx.x % L;
    const uint4* S4 = reinterpret_cast<const uint4*>(S);

    float acc[8];
#pragma unroll
    for (int q = 0; q < 8; ++q) acc[q] = 0.f;
    acc8(acc, S4[(size_t)node * stride + lane]);   // self-loop term

    int s = row_ptr[node], e = row_ptr[node + 1];
    int p = s;
    for (; p + 8 <= e; p += 8) {
        int j[8];
#pragma unroll
        for (int q = 0; q < 8; ++q) j[q] = col[p + q];
        uint4 v[8];
#pragma unroll
        for (int q = 0; q < 8; ++q) v[q] = S4[(size_t)j[q] * stride + lane];
#pragma unroll
        for (int q = 0; q < 8; ++q) acc8(acc, v[q]);
    }
    for (; p + 2 <= e; p += 2) {
        int j0 = col[p], j1 = col[p + 1];
        uint4 v0 = S4[(size_t)j0 * stride + lane];
        uint4 v1 = S4[(size_t)j1 * stride + lane];
        acc8(acc, v0); acc8(acc, v1);
    }
    for (; p < e; ++p) acc8(acc, S4[(size_t)col[p] * stride + lane]);

    float d = dis[node];
    uint4 o;
    o.x = pack2(acc[0] * d, acc[1] * d);
    o.y = pack2(acc[2] * d, acc[3] * d);
    o.z = pack2(acc[4] * d, acc[5] * d);
    o.w = pack2(acc[6] * d, acc[7] * d);
    reinterpret_cast<uint4*>(out)[(size_t)node * stride + lane] = o;
}

// ---------------- layer-1 transform: [N,10]f32 @ [10,128] + b, relu, *dis -> bf16 ----------------
__global__ __launch_bounds__(THREADS) void transform1_kernel(
        const float* __restrict__ A0, const float* __restrict__ W,
        const float* __restrict__ b, const float* __restrict__ dis,
        __hip_bfloat16* __restrict__ out, int n) {
    int t = blockIdx.x * blockDim.x + threadIdx.x;
    if (t >= n * 128) return;
    int r = t >> 7;
    int c = t & 127;
    float acc = b[c];
#pragma unroll
    for (int k = 0; k < 10; ++k)
        acc = fmaf(A0[(size_t)r * 10 + k], W[k * 128 + c], acc);
    out[(size_t)r * 128 + c] = __float2bfloat16(fmaxf(acc, 0.f) * dis[r]);
}

// ---------------- MFMA transform: bf16 [N,K] @ WT[256][K] -> 256 cols ----------------
// per wave: 16 rows x 256 cols (16 col-frags). A-frag: row=lane&15, k=(lane>>4)*8+i.
// B-frag: col=lane&15, same k.  D: col=lane&15, row=(lane>>4)*4+reg.
template <int K, bool SCALE, bool OUTF32>
__global__ __launch_bounds__(THREADS) void transform_mfma_kernel(
        const __hip_bfloat16* __restrict__ A, const __hip_bfloat16* __restrict__ WT,
        const float* __restrict__ b, const float* __restrict__ dis,
        void* __restrict__ outp, int n) {
    const int wave = threadIdx.x >> 6;
    const int lane = threadIdx.x & 63;
    const int r0 = (blockIdx.x * 4 + wave) * 16;
    if (r0 >= n) return;
    const int lrow = lane & 15;
    const int lk   = (lane >> 4) * 8;

    int arow = r0 + lrow;
    if (arow >= n) arow = n - 1;
    const uint4* Arow = reinterpret_cast<const uint4*>(A + (size_t)arow * K);
    const uint4* WT4  = reinterpret_cast<const uint4*>(WT);

    f32x4 acc[16];
#pragma unroll
    for (int t = 0; t < 16; ++t) acc[t] = (f32x4){0.f, 0.f, 0.f, 0.f};

#pragma unroll
    for (int kk = 0; kk < K; kk += 32) {
        uint4 av = Arow[(kk + lk) >> 3];
        bf16x8 af = __builtin_bit_cast(bf16x8, av);
#pragma unroll
        for (int ct = 0; ct < 16; ++ct) {
            uint4 bv = WT4[(((size_t)(ct * 16 + lrow)) * K + kk + lk) >> 3];
            bf16x8 bfr = __builtin_bit_cast(bf16x8, bv);
            acc[ct] = __builtin_amdgcn_mfma_f32_16x16x32_bf16(af, bfr, acc[ct], 0, 0, 0);
        }
    }

    const int orow0 = r0 + (lane >> 4) * 4;
    float drow[4];
#pragma unroll
    for (int r = 0; r < 4; ++r) {
        int rr = orow0 + r;
        drow[r] = SCALE ? ((rr < n) ? dis[rr] : 0.f) : 1.f;
    }
#pragma unroll
    for (int ct = 0; ct < 16; ++ct) {
        int colc = ct * 16 + lrow;
        float bias = b[colc];
#pragma unroll
        for (int r = 0; r < 4; ++r) {
            int rr = orow0 + r;
            if (rr < n) {
                float v = fmaxf(acc[ct][r] + bias, 0.f);
                if (SCALE) v *= drow[r];
                if (OUTF32)
                    reinterpret_cast<float*>(outp)[(size_t)rr * 256 + colc] = v;
                else
                    reinterpret_cast<__hip_bfloat16*>(outp)[(size_t)rr * 256 + colc] =
                        __float2bfloat16(v);
            }
        }
    }
}

// ---------------- mean pool over sorted batch ranges (f32 input) ----------------
__global__ __launch_bounds__(THREADS) void pool_kernel(
        const float* __restrict__ H, const int* __restrict__ goff,
        float* __restrict__ pooled) {
    int g = blockIdx.x;
    int c = threadIdx.x;
    int s = goff[g], e = goff[g + 1];
    float acc = 0.f;
    for (int r = s; r < e; ++r) acc += H[(size_t)r * 256 + c];
    float cnt = (float)(e - s);
    pooled[(size_t)g * 256 + c] = acc / fmaxf(cnt, 1.0f);
}

// ---------------- heads ----------------
__global__ __launch_bounds__(128) void heads_kernel(
        const float* __restrict__ pooled,
        const float* __restrict__ Wmu, const float* __restrict__ bmu,
        const float* __restrict__ Wlv, const float* __restrict__ blv,
        float* __restrict__ out, int g_total) {
    __shared__ float p[256];
    int g = blockIdx.x;
    for (int k = threadIdx.x; k < 256; k += 128) p[k] = pooled[(size_t)g * 256 + k];
    __syncthreads();
    int c = threadIdx.x & 63;
    bool is_mu = threadIdx.x < 64;
    const float* W = is_mu ? Wmu : Wlv;
    const float* bb = is_mu ? bmu : blv;
    float acc = 0.f;
    for (int k = 0; k < 256; ++k) acc = fmaf(p[k], W[k * 64 + c], acc);
    float* o = is_mu ? (out + (size_t)g * 64) : (out + (size_t)g_total * 64 + (size_t)g * 64);
    o[c] = acc + bb[c];
}

extern "C" void kernel_launch(void* const* d_in, const int* in_sizes, int n_in,
                              void* d_out, int out_size, void* d_ws, size_t ws_size,
                              hipStream_t stream) {
    const float* x      = (const float*)d_in[0];
    const int*   eidx   = (const int*)d_in[1];
    const int*   batch  = (const int*)d_in[2];
    const float* W1  = (const float*)d_in[3];
    const float* b1  = (const float*)d_in[4];
    const float* W2  = (const float*)d_in[5];
    const float* b2  = (const float*)d_in[6];
    const float* W3  = (const float*)d_in[7];
    const float* b3  = (const float*)d_in[8];
    const float* Wmu = (const float*)d_in[9];
    const float* bmu = (const float*)d_in[10];
    const float* Wlv = (const float*)d_in[11];
    const float* blv = (const float*)d_in[12];
    float* out = (float*)d_out;

    const int N = in_sizes[0] / 10;
    const int E = in_sizes[1] / 2;
    const int G = out_size / 128;

    const int* src = eidx;       // edge_index[0]
    const int* dst = eidx + E;   // edge_index[1]

    // workspace carve-up (~215 MB, same footprint as round 2)
    __hip_bfloat16* SA = (__hip_bfloat16*)d_ws;          // [N,256] bf16 ping
    __hip_bfloat16* SB = SA + (size_t)N * 256;           // [N,256] bf16 pong
    float* H3   = (float*)(SB + (size_t)N * 256);        // [N,256] f32 (layer-3 out)
    float* F0   = H3;                                    // alias: [N,10] scaled x
    float* B0   = H3 + (size_t)N * 10;                   // alias: [N,10] agg out
    float* dis  = H3 + (size_t)N * 256;                  // [N]
    float* pooled = dis + N;                             // [G,256]
    __hip_bfloat16* W2T = (__hip_bfloat16*)(pooled + (size_t)G * 256); // [256][128]
    __hip_bfloat16* W3T = W2T + 256 * 128;               // [256][256]
    int* deg     = (int*)(W3T + 256 * 256);              // [N]
    int* row_ptr = deg + N;                              // [N+1]
    int* cursor  = row_ptr + N + 1;                      // [N]
    int* col     = cursor + N;                           // [E]
    int* gcnt    = col + E;                              // [G]
    int* goff    = gcnt + G;                             // [G+1]

    const int nb_n = (N + THREADS - 1) / THREADS;
    const int nb_e = (E + THREADS - 1) / THREADS;

    // degree + norms + CSR + graph ranges + weight transposes
    init_kernel<<<nb_n, THREADS, 0, stream>>>(deg, gcnt, N, G);
    count_deg_kernel<<<nb_e, THREADS, 0, stream>>>(dst, deg, E);
    dis_kernel<<<nb_n, THREADS, 0, stream>>>(deg, dis, N);
    exscan_kernel<<<1, 1024, 0, stream>>>(deg, row_ptr, N, 1);   // indeg = deg-1
    copy_int_kernel<<<nb_n, THREADS, 0, stream>>>(row_ptr, cursor, N);
    fill_csr_kernel<<<nb_e, THREADS, 0, stream>>>(src, dst, cursor, col, E);
    batch_hist_kernel<<<nb_n, THREADS, 0, stream>>>(batch, gcnt, N);
    exscan_kernel<<<1, 1024, 0, stream>>>(gcnt, goff, G, 0);
    wt_kernel<<<(128 * 256 + THREADS - 1) / THREADS, THREADS, 0, stream>>>(W2, W2T, 128);
    wt_kernel<<<(256 * 256 + THREADS - 1) / THREADS, THREADS, 0, stream>>>(W3, W3T, 256);

    // layer 1: aggregate x*dis (10 f32 cols) then transform 10->128 -> bf16
    scale0_kernel<<<(N * 10 + THREADS - 1) / THREADS, THREADS, 0, stream>>>(x, dis, F0, N * 10);
    agg10_kernel<<<(N + 15) / 16, THREADS, 0, stream>>>(F0, row_ptr, col, dis, B0, N);
    transform1_kernel<<<((size_t)N * 128 + THREADS - 1) / THREADS, THREADS, 0, stream>>>(B0, W1, b1, dis, SA, N);

    // layer 2: aggregate S1 (128 bf16 cols) then MFMA transform 128->256 -> bf16 (*dis)
    agg_bf16_kernel<128, 16><<<(N + 15) / 16, THREADS, 0, stream>>>(SA, row_ptr, col, dis, SB, N);
    transform_mfma_kernel<128, true, false><<<(N + 63) / 64, THREADS, 0, stream>>>(SB, W2T, b2, dis, (void*)SA, N);

    // layer 3: aggregate S2 (256 bf16 cols) then MFMA transform 256->256 -> f32
    agg_bf16_kernel<256, 32><<<(N + 7) / 8, THREADS, 0, stream>>>(SA, row_ptr, col, dis, SB, N);
    transform_mfma_kernel<256, false, true><<<(N + 63) / 64, THREADS, 0, stream>>>(SB, W3T, b3, dis, (void*)H3, N);

    // mean pool + heads
    pool_kernel<<<G, THREADS, 0, stream>>>(H3, goff, pooled);
    heads_kernel<<<G, 128, 0, stream>>>(pooled, Wmu, bmu, Wlv, blv, out, G);
}

// Round 4
// 651.631 us; speedup vs baseline: 3.3060x; 1.2350x over previous
//
#include <hip/hip_runtime.h>
#include <hip/hip_bf16.h>
#include <math.h>

// GraphEncoder: 3x GCNConv (relu) -> global_mean_pool -> two linear heads.
// N=100000, E=1600000, G=2048, feats 10->128->256->256->64(x2)
//
// Round-4 strategy:
//  - transform_mfma2: B-fragments (W^T) preloaded ONCE per wave into named
//    registers (wave owns 64 cols); grid-stride over 16-row tiles with A
//    prefetched one tile ahead into a second named buffer. Round-3 version
//    had VGPR=68 -> compiler recycled staging regs -> ~130 serialized L2
//    round-trips per wave (MfmaUtil 3.4%).
//  - layer-3 output & pool input in bf16 (pool accumulates fp32).

#define THREADS 256

typedef __attribute__((ext_vector_type(8))) short bf16x8;
typedef __attribute__((ext_vector_type(4))) float f32x4;

// ---------------- init ----------------
__global__ void init_kernel(int* deg, int* gcnt, int n, int g) {
    int i = blockIdx.x * blockDim.x + threadIdx.x;
    if (i < n) deg[i] = 1;          // self-loop
    if (i < g) gcnt[i] = 0;
}

__global__ void count_deg_kernel(const int* dst, int* deg, int e) {
    int i = blockIdx.x * blockDim.x + threadIdx.x;
    if (i < e) atomicAdd(&deg[dst[i]], 1);
}

__global__ void dis_kernel(const int* deg, float* dis, int n) {
    int i = blockIdx.x * blockDim.x + threadIdx.x;
    if (i < n) dis[i] = rsqrtf((float)deg[i]);
}

// single-block exclusive scan, 1024 thr x 4 elems/chunk, wave-shfl based.
__global__ __launch_bounds__(1024) void exscan_kernel(const int* in, int* out, int n, int sub) {
    __shared__ int wsum[16];
    int carry = 0;
    const int lane = threadIdx.x & 63;
    const int wid = threadIdx.x >> 6;
    for (int base = 0; base < n; base += 4096) {
        int i0 = base + threadIdx.x * 4;
        int v[4];
#pragma unroll
        for (int q = 0; q < 4; ++q) {
            int i = i0 + q;
            v[q] = (i < n) ? (in[i] - sub) : 0;
        }
        int tsum = v[0] + v[1] + v[2] + v[3];
        int incl = tsum;
#pragma unroll
        for (int off = 1; off < 64; off <<= 1) {
            int t = __shfl_up(incl, off, 64);
            if (lane >= off) incl += t;
        }
        if (lane == 63) wsum[wid] = incl;
        __syncthreads();
        int wbase = 0;
        for (int w = 0; w < wid; ++w) wbase += wsum[w];
        int pos = incl - tsum + wbase + carry;
#pragma unroll
        for (int q = 0; q < 4; ++q) {
            int i = i0 + q;
            if (i < n) out[i] = pos;
            pos += v[q];
        }
        int tot = 0;
        for (int w = 0; w < 16; ++w) tot += wsum[w];
        carry += tot;
        __syncthreads();
    }
    if (threadIdx.x == 0) out[n] = carry;
}

__global__ void copy_int_kernel(const int* src, int* dst, int n) {
    int i = blockIdx.x * blockDim.x + threadIdx.x;
    if (i < n) dst[i] = src[i];
}

__global__ void fill_csr_kernel(const int* src, const int* dst, int* cursor,
                                int* col, int e) {
    int i = blockIdx.x * blockDim.x + threadIdx.x;
    if (i < e) {
        int d = dst[i];
        int pos = atomicAdd(&cursor[d], 1);
        col[pos] = src[i];
    }
}

__global__ void batch_hist_kernel(const int* batch, int* gcnt, int n) {
    int i = blockIdx.x * blockDim.x + threadIdx.x;
    if (i < n) atomicAdd(&gcnt[batch[i]], 1);
}

// ---------------- W [K][256] f32 -> WT [256][K] bf16 ----------------
__global__ void wt_kernel(const float* __restrict__ W, __hip_bfloat16* __restrict__ WT, int K) {
    int i = blockIdx.x * blockDim.x + threadIdx.x;
    if (i < K * 256) {
        int k = i >> 8;
        int c = i & 255;
        WT[c * K + k] = __float2bfloat16(W[i]);
    }
}

// ---------------- S0 = x * dis[row]  ([N,10] f32) ----------------
__global__ void scale0_kernel(const float* __restrict__ x, const float* __restrict__ dis,
                              float* __restrict__ out, int total) {
    int i = blockIdx.x * blockDim.x + threadIdx.x;
    if (i < total) out[i] = x[i] * dis[i / 10];
}

// ---------------- agg over 10-col f32 rows (16 lanes/node) ----------------
__global__ __launch_bounds__(THREADS) void agg10_kernel(
        const float* __restrict__ S, const int* __restrict__ row_ptr,
        const int* __restrict__ col, const float* __restrict__ dis,
        float* __restrict__ out, int n) {
    int node = blockIdx.x * 16 + threadIdx.x / 16;
    if (node >= n) return;
    int lane = threadIdx.x % 16;
    bool act = lane < 10;
    float acc = act ? S[(size_t)node * 10 + lane] : 0.f;
    int s = row_ptr[node], e = row_ptr[node + 1];
    int p = s;
    for (; p + 4 <= e; p += 4) {
        int j[4];
#pragma unroll
        for (int q = 0; q < 4; ++q) j[q] = col[p + q];
        float v[4];
#pragma unroll
        for (int q = 0; q < 4; ++q) v[q] = act ? S[(size_t)j[q] * 10 + lane] : 0.f;
        acc += v[0] + v[1] + v[2] + v[3];
    }
    for (; p < e; ++p) {
        int j = col[p];
        if (act) acc += S[(size_t)j * 10 + lane];
    }
    if (act) out[(size_t)node * 10 + lane] = acc * dis[node];
}

// ---------------- bf16 helpers ----------------
__device__ __forceinline__ void acc8(float* acc, uint4 v) {
    acc[0] += __uint_as_float(v.x << 16);
    acc[1] += __uint_as_float(v.x & 0xffff0000u);
    acc[2] += __uint_as_float(v.y << 16);
    acc[3] += __uint_as_float(v.y & 0xffff0000u);
    acc[4] += __uint_as_float(v.z << 16);
    acc[5] += __uint_as_float(v.z & 0xffff0000u);
    acc[6] += __uint_as_float(v.w << 16);
    acc[7] += __uint_as_float(v.w & 0xffff0000u);
}

__device__ __forceinline__ unsigned pack2(float a, float b) {
    unsigned short ua = __builtin_bit_cast(unsigned short, __float2bfloat16(a));
    unsigned short ub = __builtin_bit_cast(unsigned short, __float2bfloat16(b));
    return (unsigned)ua | ((unsigned)ub << 16);
}

// ---------------- agg over COLS-col bf16 rows; L = COLS/8 lanes/node ----------------
template <int COLS, int L>
__global__ __launch_bounds__(THREADS) void agg_bf16_kernel(
        const __hip_bfloat16* __restrict__ S, const int* __restrict__ row_ptr,
        const int* __restrict__ col, const float* __restrict__ dis,
        __hip_bfloat16* __restrict__ out, int n) {
    static_assert(L * 8 == COLS, "");
    constexpr int stride = COLS / 8;       // uint4 per row
    int node = blockIdx.x * (THREADS / L) + threadIdx.x / L;
    if (node >= n) return;
    int lane = threadIdx.x % L;
    const uint4* S4 = reinterpret_cast<const uint4*>(S);

    float acc[8];
#pragma unroll
    for (int q = 0; q < 8; ++q) acc[q] = 0.f;
    acc8(acc, S4[(size_t)node * stride + lane]);   // self-loop term

    int s = row_ptr[node], e = row_ptr[node + 1];
    int p = s;
    for (; p + 8 <= e; p += 8) {
        int j[8];
#pragma unroll
        for (int q = 0; q < 8; ++q) j[q] = col[p + q];
        uint4 v[8];
#pragma unroll
        for (int q = 0; q < 8; ++q) v[q] = S4[(size_t)j[q] * stride + lane];
#pragma unroll
        for (int q = 0; q < 8; ++q) acc8(acc, v[q]);
    }
    for (; p + 2 <= e; p += 2) {
        int j0 = col[p], j1 = col[p + 1];
        uint4 v0 = S4[(size_t)j0 * stride + lane];
        uint4 v1 = S4[(size_t)j1 * stride + lane];
        acc8(acc, v0); acc8(acc, v1);
    }
    for (; p < e; ++p) acc8(acc, S4[(size_t)col[p] * stride + lane]);

    float d = dis[node];
    uint4 o;
    o.x = pack2(acc[0] * d, acc[1] * d);
    o.y = pack2(acc[2] * d, acc[3] * d);
    o.z = pack2(acc[4] * d, acc[5] * d);
    o.w = pack2(acc[6] * d, acc[7] * d);
    reinterpret_cast<uint4*>(out)[(size_t)node * stride + lane] = o;
}

// ---------------- layer-1 transform: [N,10]f32 @ [10,128] + b, relu, *dis -> bf16 ----------------
__global__ __launch_bounds__(THREADS) void transform1_kernel(
        const float* __restrict__ A0, const float* __restrict__ W,
        const float* __restrict__ b, const float* __restrict__ dis,
        __hip_bfloat16* __restrict__ out, int n) {
    int t = blockIdx.x * blockDim.x + threadIdx.x;
    if (t >= n * 128) return;
    int r = t >> 7;
    int c = t & 127;
    float acc = b[c];
#pragma unroll
    for (int k = 0; k < 10; ++k)
        acc = fmaf(A0[(size_t)r * 10 + k], W[k * 128 + c], acc);
    out[(size_t)r * 128 + c] = __float2bfloat16(fmaxf(acc, 0.f) * dis[r]);
}

// ---------------- MFMA transform v2: bf16 [N,K] @ WT[256][K] -> bf16 [N,256] ----------------
// Block = 4 waves. Wave w owns cols [w*64, w*64+64): B-frags for 4 col-frags x
// K preloaded ONCE into named registers. Grid-stride over 16-row tiles; A-frag
// for the next tile prefetched into a second named buffer while computing.
// Fragment maps (m89): A row=lane&15, k=(lane>>4)*8+i. B col=lane&15, same k.
// D col=lane&15, row=(lane>>4)*4+reg.
template <int K, bool SCALE>
__global__ __launch_bounds__(THREADS) void transform_mfma2_kernel(
        const __hip_bfloat16* __restrict__ A, const __hip_bfloat16* __restrict__ WT,
        const float* __restrict__ b, const float* __restrict__ dis,
        __hip_bfloat16* __restrict__ out, int n, int ntiles) {
    constexpr int KS = K / 32;             // 4 (K=128) or 8 (K=256)
    const int wave = threadIdx.x >> 6;
    const int lane = threadIdx.x & 63;
    const int lrow = lane & 15;
    const int lk8  = (lane >> 4) * 8;      // k-element offset within a 32-k step

    // ---- preload B fragments (held for the whole kernel) ----
    const uint4* WT4 = reinterpret_cast<const uint4*>(WT);
    bf16x8 bfr[4][KS];
    float bias[4];
#pragma unroll
    for (int ct = 0; ct < 4; ++ct) {
        int colc = wave * 64 + ct * 16 + lrow;
        bias[ct] = b[colc];
#pragma unroll
        for (int kk = 0; kk < KS; ++kk)
            bfr[ct][kk] = __builtin_bit_cast(
                bf16x8, WT4[((size_t)colc * K + kk * 32 + lk8) >> 3]);
    }

    const uint4* A4 = reinterpret_cast<const uint4*>(A);
    auto loadA = [&](int t, uint4* av) {
        int row = t * 16 + lrow;
        if (row >= n) row = n - 1;
#pragma unroll
        for (int kk = 0; kk < KS; ++kk)
            av[kk] = A4[((size_t)row * K + kk * 32 + lk8) >> 3];
    };

    uint4 aC[KS], aN[KS];
    int t = blockIdx.x;
    if (t < ntiles) loadA(t, aC);

    for (; t < ntiles; t += gridDim.x) {
        int tn = t + gridDim.x;
        if (tn < ntiles) loadA(tn, aN);    // prefetch next tile

        f32x4 acc[4];
#pragma unroll
        for (int ct = 0; ct < 4; ++ct) acc[ct] = (f32x4){0.f, 0.f, 0.f, 0.f};
#pragma unroll
        for (int kk = 0; kk < KS; ++kk) {
            bf16x8 af = __builtin_bit_cast(bf16x8, aC[kk]);
#pragma unroll
            for (int ct = 0; ct < 4; ++ct)
                acc[ct] = __builtin_amdgcn_mfma_f32_16x16x32_bf16(af, bfr[ct][kk], acc[ct], 0, 0, 0);
        }

        // epilogue: bias + relu (+dis), store bf16
        const int orow0 = t * 16 + (lane >> 4) * 4;
        float dv[4];
#pragma unroll
        for (int r = 0; r < 4; ++r) {
            int rr = orow0 + r;
            dv[r] = SCALE ? ((rr < n) ? dis[rr] : 0.f) : 1.f;
        }
#pragma unroll
        for (int ct = 0; ct < 4; ++ct) {
            int colc = wave * 64 + ct * 16 + lrow;
#pragma unroll
            for (int r = 0; r < 4; ++r) {
                int rr = orow0 + r;
                if (rr < n) {
                    float v = fmaxf(acc[ct][r] + bias[ct], 0.f);
                    if (SCALE) v *= dv[r];
                    out[(size_t)rr * 256 + colc] = __float2bfloat16(v);
                }
            }
        }
#pragma unroll
        for (int kk = 0; kk < KS; ++kk) aC[kk] = aN[kk];
    }
}

// ---------------- mean pool over sorted batch ranges (bf16 input) ----------------
__global__ __launch_bounds__(THREADS) void pool_kernel(
        const __hip_bfloat16* __restrict__ H, const int* __restrict__ goff,
        float* __restrict__ pooled) {
    int g = blockIdx.x;
    int c = threadIdx.x;
    int s = goff[g], e = goff[g + 1];
    float acc = 0.f;
    for (int r = s; r < e; ++r) acc += __bfloat162float(H[(size_t)r * 256 + c]);
    float cnt = (float)(e - s);
    pooled[(size_t)g * 256 + c] = acc / fmaxf(cnt, 1.0f);
}

// ---------------- heads ----------------
__global__ __launch_bounds__(128) void heads_kernel(
        const float* __restrict__ pooled,
        const float* __restrict__ Wmu, const float* __restrict__ bmu,
        const float* __restrict__ Wlv, const float* __restrict__ blv,
        float* __restrict__ out, int g_total) {
    __shared__ float p[256];
    int g = blockIdx.x;
    for (int k = threadIdx.x; k < 256; k += 128) p[k] = pooled[(size_t)g * 256 + k];
    __syncthreads();
    int c = threadIdx.x & 63;
    bool is_mu = threadIdx.x < 64;
    const float* W = is_mu ? Wmu : Wlv;
    const float* bb = is_mu ? bmu : blv;
    float acc = 0.f;
    for (int k = 0; k < 256; ++k) acc = fmaf(p[k], W[k * 64 + c], acc);
    float* o = is_mu ? (out + (size_t)g * 64) : (out + (size_t)g_total * 64 + (size_t)g * 64);
    o[c] = acc + bb[c];
}

extern "C" void kernel_launch(void* const* d_in, const int* in_sizes, int n_in,
                              void* d_out, int out_size, void* d_ws, size_t ws_size,
                              hipStream_t stream) {
    const float* x      = (const float*)d_in[0];
    const int*   eidx   = (const int*)d_in[1];
    const int*   batch  = (const int*)d_in[2];
    const float* W1  = (const float*)d_in[3];
    const float* b1  = (const float*)d_in[4];
    const float* W2  = (const float*)d_in[5];
    const float* b2  = (const float*)d_in[6];
    const float* W3  = (const float*)d_in[7];
    const float* b3  = (const float*)d_in[8];
    const float* Wmu = (const float*)d_in[9];
    const float* bmu = (const float*)d_in[10];
    const float* Wlv = (const float*)d_in[11];
    const float* blv = (const float*)d_in[12];
    float* out = (float*)d_out;

    const int N = in_sizes[0] / 10;
    const int E = in_sizes[1] / 2;
    const int G = out_size / 128;

    const int* src = eidx;       // edge_index[0]
    const int* dst = eidx + E;   // edge_index[1]

    // workspace carve-up (~122 MB)
    __hip_bfloat16* SA = (__hip_bfloat16*)d_ws;          // [N,256] bf16 ping
    __hip_bfloat16* SB = SA + (size_t)N * 256;           // [N,256] bf16 pong
    float* F0   = (float*)(SB + (size_t)N * 256);        // [N,10] scaled x
    float* B0   = F0 + (size_t)N * 10;                   // [N,10] agg out
    float* dis  = B0 + (size_t)N * 10;                   // [N]
    float* pooled = dis + N;                             // [G,256]
    __hip_bfloat16* W2T = (__hip_bfloat16*)(pooled + (size_t)G * 256); // [256][128]
    __hip_bfloat16* W3T = W2T + 256 * 128;               // [256][256]
    int* deg     = (int*)(W3T + 256 * 256);              // [N]
    int* row_ptr = deg + N;                              // [N+1]
    int* cursor  = row_ptr + N + 1;                      // [N]
    int* col     = cursor + N;                           // [E]
    int* gcnt    = col + E;                              // [G]
    int* goff    = gcnt + G;                             // [G+1]

    const int nb_n = (N + THREADS - 1) / THREADS;
    const int nb_e = (E + THREADS - 1) / THREADS;
    const int ntiles = (N + 15) / 16;

    // degree + norms + CSR + graph ranges + weight transposes
    init_kernel<<<nb_n, THREADS, 0, stream>>>(deg, gcnt, N, G);
    count_deg_kernel<<<nb_e, THREADS, 0, stream>>>(dst, deg, E);
    dis_kernel<<<nb_n, THREADS, 0, stream>>>(deg, dis, N);
    exscan_kernel<<<1, 1024, 0, stream>>>(deg, row_ptr, N, 1);   // indeg = deg-1
    copy_int_kernel<<<nb_n, THREADS, 0, stream>>>(row_ptr, cursor, N);
    fill_csr_kernel<<<nb_e, THREADS, 0, stream>>>(src, dst, cursor, col, E);
    batch_hist_kernel<<<nb_n, THREADS, 0, stream>>>(batch, gcnt, N);
    exscan_kernel<<<1, 1024, 0, stream>>>(gcnt, goff, G, 0);
    wt_kernel<<<(128 * 256 + THREADS - 1) / THREADS, THREADS, 0, stream>>>(W2, W2T, 128);
    wt_kernel<<<(256 * 256 + THREADS - 1) / THREADS, THREADS, 0, stream>>>(W3, W3T, 256);

    // layer 1: aggregate x*dis (10 f32 cols) then transform 10->128 -> bf16
    scale0_kernel<<<(N * 10 + THREADS - 1) / THREADS, THREADS, 0, stream>>>(x, dis, F0, N * 10);
    agg10_kernel<<<(N + 15) / 16, THREADS, 0, stream>>>(F0, row_ptr, col, dis, B0, N);
    transform1_kernel<<<((size_t)N * 128 + THREADS - 1) / THREADS, THREADS, 0, stream>>>(B0, W1, b1, dis, SA, N);

    // layer 2: aggregate S1 (128 bf16 cols) then MFMA transform 128->256 (*dis)
    agg_bf16_kernel<128, 16><<<(N + 15) / 16, THREADS, 0, stream>>>(SA, row_ptr, col, dis, SB, N);
    transform_mfma2_kernel<128, true><<<512, THREADS, 0, stream>>>(SB, W2T, b2, dis, SA, N, ntiles);

    // layer 3: aggregate S2 (256 bf16 cols) then MFMA transform 256->256
    agg_bf16_kernel<256, 32><<<(N + 7) / 8, THREADS, 0, stream>>>(SA, row_ptr, col, dis, SB, N);
    transform_mfma2_kernel<256, false><<<512, THREADS, 0, stream>>>(SB, W3T, b3, dis, SA, N, ntiles);

    // mean pool + heads
    pool_kernel<<<G, THREADS, 0, stream>>>(SA, goff, pooled);
    heads_kernel<<<G, 128, 0, stream>>>(pooled, Wmu, bmu, Wlv, blv, out, G);
}